// Round 1
// baseline (191.117 us; speedup 1.0000x reference)
//
#include <hip/hip_runtime.h>
#include <math.h>

#define SR      44100.0
#define T_LEN   441000
#define B_ROWS  32
#define CHUNK   64
#define NCH     6891            // ceil(441000/64); last chunk = 40 samples
#define NTH     (B_ROWS * NCH)  // 220512
#define SPAN    27              // ceil(NCH/256)

// ws layout (floats)
#define WS_COEF 0     // 15: (b0,b1,b2,a1,a2) x 3, normalized by a0
#define WS_W0   16    // 36: A^CHUNK
#define WS_V    64    // 8*36: (A^(CHUNK*SPAN))^(2^k), k=0..7
#define WS_F    512   // NTH*6: chunk final states, overwritten with entry states by K2

__device__ __forceinline__ void matmul6(const double* X, const double* Y, double* Z) {
  for (int i = 0; i < 6; i++)
    for (int j = 0; j < 6; j++) {
      double s = 0.0;
      for (int k = 0; k < 6; k++) s += X[i*6+k] * Y[k*6+j];
      Z[i*6+j] = s;
    }
}

__global__ void k0_setup(const float* __restrict__ qs, const float* __restrict__ gains,
                         float* __restrict__ ws) {
  if (threadIdx.x != 0 || blockIdx.x != 0) return;
  double A[36];
  double u[7] = {0,0,0,0,0,0,1};  // linear form of current filter input over (S, x)
  double coef[3][5];
  for (int f = 0; f < 3; f++) {
    double cf = 100.0 * exp(log(30.0) * (double)f / 3.0);
    double w0 = 2.0 * M_PI * cf / SR;
    double alpha = sin(w0) / (2.0 * (double)qs[f]);
    double Ag = exp((double)gains[f] * (2.302585092994045684 / 40.0));  // 10^(g/40)
    double a0 = 1.0 + alpha / Ag;
    double b0 = (1.0 + alpha * Ag) / a0;
    double b1 = (-2.0 * cos(w0)) / a0;
    double b2 = (1.0 - alpha * Ag) / a0;
    double a1 = (-2.0 * cos(w0)) / a0;
    double a2 = (1.0 - alpha / Ag) / a0;
    coef[f][0]=b0; coef[f][1]=b1; coef[f][2]=b2; coef[f][3]=a1; coef[f][4]=a2;
    // TDF-II: y = b0*u + s1 ; s1' = b1*u + s2 - a1*y ; s2' = b2*u - a2*y
    double y[7], s1p[7], s2p[7];
    for (int i = 0; i < 7; i++) {
      y[i]   = b0 * u[i] + ((i == 2*f)   ? 1.0 : 0.0);
      s1p[i] = b1 * u[i] + ((i == 2*f+1) ? 1.0 : 0.0) - a1 * y[i];
      s2p[i] = b2 * u[i] - a2 * y[i];
    }
    for (int i = 0; i < 6; i++) { A[(2*f)*6+i] = s1p[i]; A[(2*f+1)*6+i] = s2p[i]; }
    for (int i = 0; i < 7; i++) u[i] = y[i];
  }
  // W = A^64 (6 squarings)
  double W[36], Tmp[36];
  for (int i = 0; i < 36; i++) W[i] = A[i];
  for (int s = 0; s < 6; s++) { matmul6(W, W, Tmp); for (int i = 0; i < 36; i++) W[i] = Tmp[i]; }
  // V = W^27 = W^16 * W^8 * W^2 * W
  double P2[36], P4[36], P8[36], P16[36], V[36], T2[36];
  matmul6(W, W, P2); matmul6(P2, P2, P4); matmul6(P4, P4, P8); matmul6(P8, P8, P16);
  matmul6(P16, P8, Tmp); matmul6(Tmp, P2, T2); matmul6(T2, W, V);
  // store
  for (int f = 0; f < 3; f++)
    for (int j = 0; j < 5; j++) ws[WS_COEF + f*5 + j] = (float)coef[f][j];
  for (int i = 0; i < 36; i++) ws[WS_W0 + i] = (float)W[i];
  double Vk[36];
  for (int i = 0; i < 36; i++) Vk[i] = V[i];
  for (int k = 0; k < 8; k++) {
    for (int i = 0; i < 36; i++) ws[WS_V + k*36 + i] = (float)Vk[i];
    matmul6(Vk, Vk, Tmp);
    for (int i = 0; i < 36; i++) Vk[i] = Tmp[i];
  }
}

#define LOAD_COEFS(cf) \
  const float b00=cf[0],b10=cf[1],b20=cf[2],a10=cf[3],a20=cf[4]; \
  const float b01=cf[5],b11=cf[6],b21=cf[7],a11=cf[8],a21=cf[9]; \
  const float b02=cf[10],b12=cf[11],b22=cf[12],a12=cf[13],a22=cf[14];

#define CASCADE_STEP(xx) do { \
    float y1 = fmaf(b00, (xx), s11); \
    s11 = fmaf(-a10, y1, fmaf(b10, (xx), s21)); \
    s21 = fmaf(-a20, y1, b20 * (xx)); \
    float y2 = fmaf(b01, y1, s12); \
    s12 = fmaf(-a11, y2, fmaf(b11, y1, s22)); \
    s22 = fmaf(-a21, y2, b21 * y1); \
    y3 = fmaf(b02, y2, s13); \
    s13 = fmaf(-a12, y3, fmaf(b12, y2, s23)); \
    s23 = fmaf(-a22, y3, b22 * y2); \
  } while (0)

__global__ __launch_bounds__(256) void k1_states(const float* __restrict__ x,
                                                 float* __restrict__ ws) {
  int tid = blockIdx.x * 256 + threadIdx.x;
  if (tid >= NTH) return;
  int row = tid / NCH, ci = tid % NCH;
  const float* cf = ws + WS_COEF;
  LOAD_COEFS(cf);
  long base = (long)row * T_LEN + (long)ci * CHUNK;
  int rem = min(CHUNK, T_LEN - ci * CHUNK);
  int n4 = rem >> 2;
  const float4* xp = (const float4*)(x + base);
  float s11=0,s21=0,s12=0,s22=0,s13=0,s23=0;
  float y3;
  float4 cur = xp[0];
  for (int j = 0; j < n4; j++) {
    float4 nxt = (j + 1 < n4) ? xp[j + 1] : make_float4(0, 0, 0, 0);
    #pragma unroll
    for (int e = 0; e < 4; e++) {
      float xx = (e == 0) ? cur.x : (e == 1) ? cur.y : (e == 2) ? cur.z : cur.w;
      CASCADE_STEP(xx);
    }
    cur = nxt;
  }
  float* F = ws + WS_F + (long)tid * 6;
  F[0]=s11; F[1]=s21; F[2]=s12; F[3]=s22; F[4]=s13; F[5]=s23;
}

__global__ __launch_bounds__(256) void k2_scan(float* __restrict__ ws) {
  int row = blockIdx.x, t = threadIdx.x;
  __shared__ float bufA[256][6], bufB[256][6];
  const float* W0 = ws + WS_W0;
  float W[36];
  #pragma unroll
  for (int i = 0; i < 36; i++) W[i] = W0[i];
  float* F = ws + WS_F + (long)row * NCH * 6;
  int j0 = t * SPAN, j1 = min(j0 + SPAN, NCH);
  // Phase A: fold own span from zero state
  float v[6] = {0,0,0,0,0,0};
  for (int j = j0; j < j1; j++) {
    const float* Fj = F + (long)j * 6;
    float nv[6];
    #pragma unroll
    for (int i = 0; i < 6; i++) {
      float s = Fj[i];
      #pragma unroll
      for (int k = 0; k < 6; k++) s = fmaf(W[i*6+k], v[k], s);
      nv[i] = s;
    }
    #pragma unroll
    for (int i = 0; i < 6; i++) v[i] = nv[i];
  }
  #pragma unroll
  for (int i = 0; i < 6; i++) bufA[t][i] = v[i];
  __syncthreads();
  // Phase B: Hillis-Steele inclusive scan over 256 partials (ping-pong)
  float (*src)[6] = bufA, (*dst)[6] = bufB;
  for (int k = 0; k < 8; k++) {
    int d = 1 << k;
    const float* Vk = ws + WS_V + k * 36;
    float nv[6];
    if (t >= d) {
      #pragma unroll
      for (int i = 0; i < 6; i++) {
        float s = src[t][i];
        #pragma unroll
        for (int kk = 0; kk < 6; kk++) s = fmaf(Vk[i*6+kk], src[t-d][kk], s);
        nv[i] = s;
      }
    } else {
      #pragma unroll
      for (int i = 0; i < 6; i++) nv[i] = src[t][i];
    }
    #pragma unroll
    for (int i = 0; i < 6; i++) dst[t][i] = nv[i];
    __syncthreads();
    float (*tmp)[6] = src; src = dst; dst = tmp;
  }
  // exclusive: entry state of chunk j0
  float e[6];
  if (t > 0) { for (int i = 0; i < 6; i++) e[i] = src[t-1][i]; }
  else       { for (int i = 0; i < 6; i++) e[i] = 0.0f; }
  // Phase C: walk span, overwrite F[j] with entry state of chunk j
  for (int j = j0; j < j1; j++) {
    float* Fj = F + (long)j * 6;
    float nv[6];
    #pragma unroll
    for (int i = 0; i < 6; i++) {
      float s = Fj[i];
      #pragma unroll
      for (int k = 0; k < 6; k++) s = fmaf(W[i*6+k], e[k], s);
      nv[i] = s;
    }
    #pragma unroll
    for (int i = 0; i < 6; i++) { Fj[i] = e[i]; e[i] = nv[i]; }
  }
}

__global__ __launch_bounds__(256) void k3_emit(const float* __restrict__ x,
                                               float* __restrict__ y,
                                               const float* __restrict__ ws) {
  int tid = blockIdx.x * 256 + threadIdx.x;
  if (tid >= NTH) return;
  int row = tid / NCH, ci = tid % NCH;
  const float* cf = ws + WS_COEF;
  LOAD_COEFS(cf);
  const float* E = ws + WS_F + (long)tid * 6;
  float s11=E[0], s21=E[1], s12=E[2], s22=E[3], s13=E[4], s23=E[5];
  long base = (long)row * T_LEN + (long)ci * CHUNK;
  int rem = min(CHUNK, T_LEN - ci * CHUNK);
  int n4 = rem >> 2;
  const float4* xp = (const float4*)(x + base);
  float4* yp = (float4*)(y + base);
  float y3;
  float4 cur = xp[0];
  for (int j = 0; j < n4; j++) {
    float4 nxt = (j + 1 < n4) ? xp[j + 1] : make_float4(0, 0, 0, 0);
    float4 o;
    {
      float xx = cur.x; CASCADE_STEP(xx); o.x = y3;
      xx = cur.y; CASCADE_STEP(xx); o.y = y3;
      xx = cur.z; CASCADE_STEP(xx); o.z = y3;
      xx = cur.w; CASCADE_STEP(xx); o.w = y3;
    }
    yp[j] = o;
    cur = nxt;
  }
}

extern "C" void kernel_launch(void* const* d_in, const int* in_sizes, int n_in,
                              void* d_out, int out_size, void* d_ws, size_t ws_size,
                              hipStream_t stream) {
  const float* audio = (const float*)d_in[0];
  const float* qs    = (const float*)d_in[1];
  const float* gains = (const float*)d_in[2];
  float* out = (float*)d_out;
  float* ws  = (float*)d_ws;

  hipLaunchKernelGGL(k0_setup, dim3(1), dim3(1), 0, stream, qs, gains, ws);
  int blocks = (NTH + 255) / 256;
  hipLaunchKernelGGL(k1_states, dim3(blocks), dim3(256), 0, stream, audio, ws);
  hipLaunchKernelGGL(k2_scan, dim3(B_ROWS), dim3(256), 0, stream, ws);
  hipLaunchKernelGGL(k3_emit, dim3(blocks), dim3(256), 0, stream, audio, out, ws);
}

// Round 2
// 84.139 us; speedup vs baseline: 2.2715x; 2.2715x over previous
//
#include <hip/hip_runtime.h>
#include <math.h>

#define SR      44100.0
#define T_LEN   441000
#define B_ROWS  32
#define CHUNK   64
#define NCH     6891            // ceil(441000/64); last chunk = 40 samples
#define NTH     (B_ROWS * NCH)  // 220512 chunks total
#define WPR     108             // waves per row = ceil(NCH/64)
#define NWAVE   (B_ROWS * WPR)  // 3456
#define WAVES_PER_BLK 3
#define NBLK    (NWAVE / WAVES_PER_BLK)  // 1152
#define K2_THREADS 1024
#define SPAN    7               // chunks per k2 thread: 1024*7 = 7168 >= 6891
#define K2_ROUNDS 10

// ws layout (floats)
#define WS_COEF 0     // 15
#define WS_W0   16    // 36: A^64
#define WS_V    64    // 10*36: (A^(64*7))^(2^k), k=0..9
#define WS_F    448   // NTH*6: chunk final states -> entry states after k2

// LDS slab per wave: 64 rows (chunks) x 68 floats (64 + pad4; float4 stride 17)
#define ROW_F   68
#define SLAB_F  (64 * ROW_F)    // 4352 floats = 17408 B

// ---------------- k0: coefficients + matrix powers (1 wave) ----------------

__device__ __forceinline__ void mm6(const double* X, const double* Y, double* Z, int t) {
  if (t < 36) {
    int i = t / 6, j = t % 6;
    double s = 0.0;
    #pragma unroll
    for (int k = 0; k < 6; k++) s += X[i*6+k] * Y[k*6+j];
    Z[t] = s;
  }
}

__global__ __launch_bounds__(64) void k0_setup(const float* __restrict__ qs,
                                               const float* __restrict__ gains,
                                               float* __restrict__ ws) {
  __shared__ double P[36], Q[36], R[36], S[36];
  int t = threadIdx.x;
  if (t == 0) {
    double u[7] = {0,0,0,0,0,0,1};  // linear form of current filter input over (S, x)
    for (int f = 0; f < 3; f++) {
      double cf = 100.0 * exp(log(30.0) * (double)f / 3.0);
      double w0 = 2.0 * M_PI * cf / SR;
      double alpha = sin(w0) / (2.0 * (double)qs[f]);
      double Ag = exp((double)gains[f] * (2.302585092994045684 / 40.0));  // 10^(g/40)
      double a0 = 1.0 + alpha / Ag;
      double b0 = (1.0 + alpha * Ag) / a0;
      double b1 = (-2.0 * cos(w0)) / a0;
      double b2 = (1.0 - alpha * Ag) / a0;
      double a1 = (-2.0 * cos(w0)) / a0;
      double a2 = (1.0 - alpha / Ag) / a0;
      ws[WS_COEF + f*5 + 0] = (float)b0;
      ws[WS_COEF + f*5 + 1] = (float)b1;
      ws[WS_COEF + f*5 + 2] = (float)b2;
      ws[WS_COEF + f*5 + 3] = (float)a1;
      ws[WS_COEF + f*5 + 4] = (float)a2;
      // TDF-II: y = b0*u + s1 ; s1' = b1*u + s2 - a1*y ; s2' = b2*u - a2*y
      double y[7], s1p[7], s2p[7];
      for (int i = 0; i < 7; i++) {
        y[i]   = b0 * u[i] + ((i == 2*f)   ? 1.0 : 0.0);
        s1p[i] = b1 * u[i] + ((i == 2*f+1) ? 1.0 : 0.0) - a1 * y[i];
        s2p[i] = b2 * u[i] - a2 * y[i];
      }
      for (int i = 0; i < 6; i++) { P[(2*f)*6+i] = s1p[i]; P[(2*f+1)*6+i] = s2p[i]; }
      for (int i = 0; i < 7; i++) u[i] = y[i];
    }
  }
  __syncthreads();
  // W = A^64 via 6 squarings, ping-pong P<->Q (ends in P)
  double* cur = P; double* oth = Q;
  for (int s = 0; s < 6; s++) {
    mm6(cur, cur, oth, t); __syncthreads();
    double* tmp = cur; cur = oth; oth = tmp;
  }
  // cur == P == W
  if (t < 36) ws[WS_W0 + t] = (float)cur[t];
  mm6(cur, cur, Q, t); __syncthreads();   // Q = W^2
  mm6(Q, Q, R, t); __syncthreads();       // R = W^4
  mm6(R, Q, S, t); __syncthreads();       // S = W^6
  mm6(S, cur, Q, t); __syncthreads();     // Q = W^7 = V
  double* vc = Q; double* vo = R;
  for (int k = 0; k < K2_ROUNDS; k++) {
    if (t < 36) ws[WS_V + k*36 + t] = (float)vc[k == 0 ? t : t];
    __syncthreads();
    mm6(vc, vc, vo, t); __syncthreads();
    double* tmp = vc; vc = vo; vo = tmp;
  }
}

// ---------------- shared cascade helpers ----------------

#define LOAD_COEFS(cf) \
  const float b00=cf[0],b10=cf[1],b20=cf[2],a10=cf[3],a20=cf[4]; \
  const float b01=cf[5],b11=cf[6],b21=cf[7],a11=cf[8],a21=cf[9]; \
  const float b02=cf[10],b12=cf[11],b22=cf[12],a12=cf[13],a22=cf[14];

#define CASCADE_STEP(xx) do { \
    float y1 = fmaf(b00, (xx), s11); \
    s11 = fmaf(-a10, y1, fmaf(b10, (xx), s21)); \
    s21 = fmaf(-a20, y1, b20 * (xx)); \
    float y2 = fmaf(b01, y1, s12); \
    s12 = fmaf(-a11, y2, fmaf(b11, y1, s22)); \
    s22 = fmaf(-a21, y2, b21 * y1); \
    y3 = fmaf(b02, y2, s13); \
    s13 = fmaf(-a12, y3, fmaf(b12, y2, s23)); \
    s23 = fmaf(-a22, y3, b22 * y2); \
  } while (0)

// ---------------- k1: chunk final states (zero entry) ----------------

__global__ __launch_bounds__(192) void k1_states(const float* __restrict__ x,
                                                 float* __restrict__ ws) {
  __shared__ float lds[WAVES_PER_BLK * SLAB_F];
  int wib  = threadIdx.x >> 6;
  int lane = threadIdx.x & 63;
  int gw   = blockIdx.x * WAVES_PER_BLK + wib;
  int row  = gw / WPR, wci = gw % WPR;
  long rowbase = (long)row * T_LEN;
  int s0   = wci * 4096;                 // sample offset in row
  int span = min(4096, T_LEN - s0);      // floats in this wave's region
  int span4 = span >> 2;
  const float4* xp = (const float4*)(x + rowbase + s0);
  float* slab = lds + wib * SLAB_F;

  #pragma unroll
  for (int i = 0; i < 16; i++) {
    int g4 = i * 64 + lane;
    if (g4 < span4) {
      float4 v = xp[g4];
      int tt = g4 >> 4, j4 = g4 & 15;
      *(float4*)(slab + tt * ROW_F + 4 * j4) = v;
    }
  }
  __syncthreads();

  int ci = wci * 64 + lane;
  if (ci < NCH) {
    const float* cf = ws + WS_COEF;
    LOAD_COEFS(cf);
    int rem = min(CHUNK, T_LEN - ci * CHUNK);
    int n4 = rem >> 2;
    const float* rowp = slab + lane * ROW_F;
    float s11=0,s21=0,s12=0,s22=0,s13=0,s23=0;
    float y3;
    for (int j4 = 0; j4 < n4; j4++) {
      float4 v = *(const float4*)(rowp + 4 * j4);
      CASCADE_STEP(v.x); CASCADE_STEP(v.y); CASCADE_STEP(v.z); CASCADE_STEP(v.w);
    }
    (void)y3;
    float* F = ws + WS_F + (long)(row * NCH + ci) * 6;
    F[0]=s11; F[1]=s21; F[2]=s12; F[3]=s22; F[4]=s13; F[5]=s23;
  }
}

// ---------------- k2: per-row affine scan over chunk states ----------------

__global__ __launch_bounds__(K2_THREADS) void k2_scan(float* __restrict__ ws) {
  int row = blockIdx.x, t = threadIdx.x;
  __shared__ float bufA[K2_THREADS][7], bufB[K2_THREADS][7];
  const float* W0 = ws + WS_W0;
  float W[36];
  #pragma unroll
  for (int i = 0; i < 36; i++) W[i] = W0[i];
  float* F = ws + WS_F + (long)row * NCH * 6;
  int j0 = t * SPAN, j1 = min(j0 + SPAN, NCH);
  // Phase A: fold own span from zero state
  float v[6] = {0,0,0,0,0,0};
  for (int j = j0; j < j1; j++) {
    const float* Fj = F + (long)j * 6;
    float nv[6];
    #pragma unroll
    for (int i = 0; i < 6; i++) {
      float s = Fj[i];
      #pragma unroll
      for (int k = 0; k < 6; k++) s = fmaf(W[i*6+k], v[k], s);
      nv[i] = s;
    }
    #pragma unroll
    for (int i = 0; i < 6; i++) v[i] = nv[i];
  }
  #pragma unroll
  for (int i = 0; i < 6; i++) bufA[t][i] = v[i];
  __syncthreads();
  // Phase B: Hillis-Steele inclusive scan (wrong values only in unused tail)
  float (*src)[7] = bufA, (*dst)[7] = bufB;
  for (int k = 0; k < K2_ROUNDS; k++) {
    int d = 1 << k;
    const float* Vk = ws + WS_V + k * 36;
    float nv[6];
    if (t >= d) {
      #pragma unroll
      for (int i = 0; i < 6; i++) {
        float s = src[t][i];
        #pragma unroll
        for (int kk = 0; kk < 6; kk++) s = fmaf(Vk[i*6+kk], src[t-d][kk], s);
        nv[i] = s;
      }
    } else {
      #pragma unroll
      for (int i = 0; i < 6; i++) nv[i] = src[t][i];
    }
    #pragma unroll
    for (int i = 0; i < 6; i++) dst[t][i] = nv[i];
    __syncthreads();
    float (*tmp)[7] = src; src = dst; dst = tmp;
  }
  float e[6];
  if (t > 0) { for (int i = 0; i < 6; i++) e[i] = src[t-1][i]; }
  else       { for (int i = 0; i < 6; i++) e[i] = 0.0f; }
  // Phase C: overwrite F[j] with entry state of chunk j
  for (int j = j0; j < j1; j++) {
    float* Fj = F + (long)j * 6;
    float nv[6];
    #pragma unroll
    for (int i = 0; i < 6; i++) {
      float s = Fj[i];
      #pragma unroll
      for (int k = 0; k < 6; k++) s = fmaf(W[i*6+k], e[k], s);
      nv[i] = s;
    }
    #pragma unroll
    for (int i = 0; i < 6; i++) { Fj[i] = e[i]; e[i] = nv[i]; }
  }
}

// ---------------- k3: exact emit from entry states ----------------

__global__ __launch_bounds__(192) void k3_emit(const float* __restrict__ x,
                                               float* __restrict__ y,
                                               const float* __restrict__ ws) {
  __shared__ float lds[WAVES_PER_BLK * SLAB_F];
  int wib  = threadIdx.x >> 6;
  int lane = threadIdx.x & 63;
  int gw   = blockIdx.x * WAVES_PER_BLK + wib;
  int row  = gw / WPR, wci = gw % WPR;
  long rowbase = (long)row * T_LEN;
  int s0   = wci * 4096;
  int span = min(4096, T_LEN - s0);
  int span4 = span >> 2;
  const float4* xp = (const float4*)(x + rowbase + s0);
  float* slab = lds + wib * SLAB_F;

  #pragma unroll
  for (int i = 0; i < 16; i++) {
    int g4 = i * 64 + lane;
    if (g4 < span4) {
      float4 v = xp[g4];
      int tt = g4 >> 4, j4 = g4 & 15;
      *(float4*)(slab + tt * ROW_F + 4 * j4) = v;
    }
  }
  __syncthreads();

  int ci = wci * 64 + lane;
  if (ci < NCH) {
    const float* cf = ws + WS_COEF;
    LOAD_COEFS(cf);
    const float* E = ws + WS_F + (long)(row * NCH + ci) * 6;
    float s11=E[0], s21=E[1], s12=E[2], s22=E[3], s13=E[4], s23=E[5];
    int rem = min(CHUNK, T_LEN - ci * CHUNK);
    int n4 = rem >> 2;
    float* rowp = slab + lane * ROW_F;
    float y3;
    for (int j4 = 0; j4 < n4; j4++) {
      float4 v = *(const float4*)(rowp + 4 * j4);
      float4 o;
      CASCADE_STEP(v.x); o.x = y3;
      CASCADE_STEP(v.y); o.y = y3;
      CASCADE_STEP(v.z); o.z = y3;
      CASCADE_STEP(v.w); o.w = y3;
      *(float4*)(rowp + 4 * j4) = o;
    }
  }
  __syncthreads();

  float4* yp = (float4*)(y + rowbase + s0);
  #pragma unroll
  for (int i = 0; i < 16; i++) {
    int g4 = i * 64 + lane;
    if (g4 < span4) {
      int tt = g4 >> 4, j4 = g4 & 15;
      yp[g4] = *(const float4*)(slab + tt * ROW_F + 4 * j4);
    }
  }
}

extern "C" void kernel_launch(void* const* d_in, const int* in_sizes, int n_in,
                              void* d_out, int out_size, void* d_ws, size_t ws_size,
                              hipStream_t stream) {
  const float* audio = (const float*)d_in[0];
  const float* qs    = (const float*)d_in[1];
  const float* gains = (const float*)d_in[2];
  float* out = (float*)d_out;
  float* ws  = (float*)d_ws;

  hipLaunchKernelGGL(k0_setup, dim3(1), dim3(64), 0, stream, qs, gains, ws);
  hipLaunchKernelGGL(k1_states, dim3(NBLK), dim3(192), 0, stream, audio, ws);
  hipLaunchKernelGGL(k2_scan, dim3(B_ROWS), dim3(K2_THREADS), 0, stream, ws);
  hipLaunchKernelGGL(k3_emit, dim3(NBLK), dim3(192), 0, stream, audio, out, ws);
}

// Round 3
// 64.981 us; speedup vs baseline: 2.9411x; 1.2948x over previous
//
#include <hip/hip_runtime.h>
#include <math.h>

#define SR      44100.0
#define T_LEN   441000
#define B_ROWS  32
#define CHUNK   32
#define NCH     13782           // ceil(441000/32); last chunk = 8 samples
#define WPR     216             // waves per row = ceil(NCH/64)
#define NWAVE   (B_ROWS * WPR)  // 6912
#define NBLK    (NWAVE / 4)     // 1728 blocks of 4 waves
#define NSEG    8
#define SEGCH   1724            // chunks per segment (segs 0..6); seg 7 = 1714 (even)

// ws layout (floats)
#define WS_COEF 0               // 15
#define WS_W    16              // 36: W = A^32
#define WS_G    64              // 36: G = W^1724 (one full segment)
#define WS_V    128             // 10*36: Vk = W^(2*2^k), k=0..9
#define WS_T    512             // 256*6: segment totals
#define WS_E    2048            // 256*1024*6: per-thread exclusive (rel) entries
#define WS_F    1574912         // NCH*B_ROWS*6: chunk finals -> chunk entries

typedef __attribute__((address_space(1))) const void gconst_t;
typedef __attribute__((address_space(3))) void lds_t;
#define GL2LDS(gp, lp) __builtin_amdgcn_global_load_lds((gconst_t*)(gp), (lds_t*)(lp), 16, 0, 0)

// ---------------- k0: coefficients + matrix powers (1 block, 64 thr) ----------------

__device__ __forceinline__ void mm6(const double* X, const double* Y, double* Z, int t) {
  if (t < 36) {
    int i = t / 6, j = t % 6;
    double s = 0.0;
    #pragma unroll
    for (int k = 0; k < 6; k++) s += X[i*6+k] * Y[k*6+j];
    Z[t] = s;
  }
}

__global__ __launch_bounds__(64) void k0_setup(const float* __restrict__ qs,
                                               const float* __restrict__ gains,
                                               float* __restrict__ ws) {
  __shared__ double dco[3][5];
  __shared__ double M0[36], M1[36];
  __shared__ double Vd[10][36];
  int t = threadIdx.x;
  if (t < 3) {
    int f = t;
    double cf = 100.0 * exp(log(30.0) * (double)f / 3.0);
    double w0 = 2.0 * M_PI * cf / SR;
    double alpha = sin(w0) / (2.0 * (double)qs[f]);
    double Ag = exp((double)gains[f] * (2.302585092994045684 / 40.0));  // 10^(g/40)
    double a0 = 1.0 + alpha / Ag;
    dco[f][0] = (1.0 + alpha * Ag) / a0;
    dco[f][1] = (-2.0 * cos(w0)) / a0;
    dco[f][2] = (1.0 - alpha * Ag) / a0;
    dco[f][3] = (-2.0 * cos(w0)) / a0;
    dco[f][4] = (1.0 - alpha / Ag) / a0;
  }
  __syncthreads();
  if (t < 15) ws[WS_COEF + t] = (float)dco[t/5][t%5];
  if (t == 0) {
    // Build 6x6 one-sample cascade matrix A (TDF-II states, 2 per filter)
    double u[7] = {0,0,0,0,0,0,1};  // current filter input as linear form over (S, x)
    for (int f = 0; f < 3; f++) {
      double b0=dco[f][0], b1=dco[f][1], b2=dco[f][2], a1=dco[f][3], a2=dco[f][4];
      double yv[7], s1p[7], s2p[7];
      for (int i = 0; i < 7; i++) {
        yv[i]  = b0 * u[i] + ((i == 2*f)   ? 1.0 : 0.0);
        s1p[i] = b1 * u[i] + ((i == 2*f+1) ? 1.0 : 0.0) - a1 * yv[i];
        s2p[i] = b2 * u[i] - a2 * yv[i];
      }
      for (int i = 0; i < 6; i++) { M0[(2*f)*6+i] = s1p[i]; M0[(2*f+1)*6+i] = s2p[i]; }
      for (int i = 0; i < 7; i++) u[i] = yv[i];
    }
  }
  __syncthreads();
  // W = A^32 via 5 squarings (ping-pong M0<->M1; ends in M1)
  double* cur = M0; double* oth = M1;
  for (int s = 0; s < 5; s++) {
    mm6(cur, cur, oth, t); __syncthreads();
    double* tm = cur; cur = oth; oth = tm;
  }
  if (t < 36) ws[WS_W + t] = (float)cur[t];
  // Vd[k] = W^(2*2^k), k=0..9
  mm6(cur, cur, Vd[0], t); __syncthreads();
  for (int k = 1; k < 10; k++) { mm6(Vd[k-1], Vd[k-1], Vd[k], t); __syncthreads(); }
  if (t < 36) for (int k = 0; k < 10; k++) ws[WS_V + k*36 + t] = (float)Vd[k][t];
  // G = W^1724 = W^(4+8+16+32+128+512+1024) = V1*V2*V3*V4*V6*V8*V9
  mm6(Vd[1], Vd[2], oth, t); __syncthreads();   // W^12
  mm6(oth, Vd[3], cur, t); __syncthreads();     // W^28
  mm6(cur, Vd[4], oth, t); __syncthreads();     // W^60
  mm6(oth, Vd[6], cur, t); __syncthreads();     // W^188
  mm6(cur, Vd[8], oth, t); __syncthreads();     // W^700
  mm6(oth, Vd[9], cur, t); __syncthreads();     // W^1724
  if (t < 36) ws[WS_G + t] = (float)cur[t];
}

// ---------------- shared cascade helpers ----------------

#define LOAD_COEFS(cf) \
  const float b00=cf[0],b10=cf[1],b20=cf[2],a10=cf[3],a20=cf[4]; \
  const float b01=cf[5],b11=cf[6],b21=cf[7],a11=cf[8],a21=cf[9]; \
  const float b02=cf[10],b12=cf[11],b22=cf[12],a12=cf[13],a22=cf[14];

#define CASCADE_STEP(xx) do { \
    float y1 = fmaf(b00, (xx), s11); \
    s11 = fmaf(-a10, y1, fmaf(b10, (xx), s21)); \
    s21 = fmaf(-a20, y1, b20 * (xx)); \
    float y2 = fmaf(b01, y1, s12); \
    s12 = fmaf(-a11, y2, fmaf(b11, y1, s22)); \
    s22 = fmaf(-a21, y2, b21 * y1); \
    y3 = fmaf(b02, y2, s13); \
    s13 = fmaf(-a12, y3, fmaf(b12, y2, s23)); \
    s23 = fmaf(-a22, y3, b22 * y2); \
  } while (0)

// Per-wave slab: 64 chunks x 32 floats, linear (ROW_F=32, no pad).
// Swizzle: LDS float4-slot s holds global float4 g(s) = (s&~7)|((s&7)^((s>>3)&7)).
// (involution; keeps coalescing within each 128B line; ds_read_b128 bank-balanced)

// ---------------- k1: chunk final states (zero entry) ----------------

__global__ __launch_bounds__(256) void k1_states(const float* __restrict__ x,
                                                 float* __restrict__ ws) {
  __shared__ float lds[4 * 2048];   // 4 waves x 8KB
  int wib = threadIdx.x >> 6, lane = threadIdx.x & 63;
  int gw = blockIdx.x * 4 + wib;
  int row = gw / WPR, wci = gw % WPR;
  long rowbase = (long)row * T_LEN;
  int s0 = wci << 11;                                // sample offset
  int span4 = (min(2048, T_LEN - s0)) >> 2;          // float4 count (512 or 170)
  const float4* xp = (const float4*)(x + rowbase + s0);
  float* slab = lds + (wib << 11);
  if (span4 == 512) {
    #pragma unroll
    for (int i = 0; i < 8; i++) {
      int s = (i << 6) + lane;
      int g = (s & ~7) | ((s & 7) ^ ((s >> 3) & 7));
      GL2LDS(xp + g, slab + (i << 8));
    }
  } else {
    #pragma unroll
    for (int i = 0; i < 8; i++) {
      int s = (i << 6) + lane;
      int g = (s & ~7) | ((s & 7) ^ ((s >> 3) & 7));
      if (g < span4) GL2LDS(xp + g, slab + (i << 8));
    }
  }
  __syncthreads();
  int ci = (wci << 6) + lane;
  if (ci < NCH) {
    const float* cf = ws + WS_COEF;
    LOAD_COEFS(cf);
    int rem = min(CHUNK, T_LEN - (ci << 5));
    int n4 = rem >> 2;                               // 8, or 2 for last chunk
    const float* rowp = slab + (lane << 5);
    int xr = lane & 7;
    float s11=0,s21=0,s12=0,s22=0,s13=0,s23=0, y3;
    if (n4 == 8) {
      #pragma unroll
      for (int j4 = 0; j4 < 8; j4++) {
        float4 v = *(const float4*)(rowp + ((j4 ^ xr) << 2));
        CASCADE_STEP(v.x); CASCADE_STEP(v.y); CASCADE_STEP(v.z); CASCADE_STEP(v.w);
      }
    } else {
      for (int j4 = 0; j4 < n4; j4++) {
        float4 v = *(const float4*)(rowp + ((j4 ^ xr) << 2));
        CASCADE_STEP(v.x); CASCADE_STEP(v.y); CASCADE_STEP(v.z); CASCADE_STEP(v.w);
      }
    }
    (void)y3;
    float* F = ws + WS_F + ((long)row * NCH + ci) * 6;
    F[0]=s11; F[1]=s21; F[2]=s12; F[3]=s22; F[4]=s13; F[5]=s23;
  }
}

// ---------------- k2a: per-segment fold + block scan (256 blocks) ----------------

__global__ __launch_bounds__(1024) void k2a(float* __restrict__ ws) {
  int seg = blockIdx.x & 7, row = blockIdx.x >> 3, t = threadIdx.x;
  __shared__ float bufA[1024][7], bufB[1024][7];
  __shared__ float sW[36], sV[10][36];
  for (int i = t; i < 36; i += 1024) sW[i] = ws[WS_W + i];
  for (int i = t; i < 360; i += 1024) sV[i/36][i%36] = ws[WS_V + i];
  int segstart = seg * SEGCH;
  int nch = min(SEGCH, NCH - segstart);
  int nact = nch >> 1;             // 862 (or 857 for seg 7); all items full 2-chunk
  __syncthreads();
  const float* F = ws + WS_F + ((long)row * NCH + segstart) * 6;
  float v[6] = {0,0,0,0,0,0};
  if (t < nact) {
    #pragma unroll
    for (int c = 0; c < 2; c++) {
      const float* Fj = F + (long)(2*t + c) * 6;
      float nv[6];
      #pragma unroll
      for (int i = 0; i < 6; i++) {
        float s = Fj[i];
        #pragma unroll
        for (int k = 0; k < 6; k++) s = fmaf(sW[i*6+k], v[k], s);
        nv[i] = s;
      }
      #pragma unroll
      for (int i = 0; i < 6; i++) v[i] = nv[i];
    }
  }
  #pragma unroll
  for (int i = 0; i < 6; i++) bufA[t][i] = v[i];
  __syncthreads();
  float (*src)[7] = bufA, (*dst)[7] = bufB;
  for (int k = 0; k < 10; k++) {
    int d = 1 << k;
    float nv[6];
    if (t >= d) {
      #pragma unroll
      for (int i = 0; i < 6; i++) {
        float s = src[t][i];
        #pragma unroll
        for (int kk = 0; kk < 6; kk++) s = fmaf(sV[k][i*6+kk], src[t-d][kk], s);
        nv[i] = s;
      }
    } else {
      #pragma unroll
      for (int i = 0; i < 6; i++) nv[i] = src[t][i];
    }
    #pragma unroll
    for (int i = 0; i < 6; i++) dst[t][i] = nv[i];
    __syncthreads();
    float (*tm)[7] = src; src = dst; dst = tm;
  }
  float* Ep = ws + WS_E + ((long)blockIdx.x * 1024 + t) * 6;
  if (t > 0) {
    #pragma unroll
    for (int i = 0; i < 6; i++) Ep[i] = src[t-1][i];
  } else {
    #pragma unroll
    for (int i = 0; i < 6; i++) Ep[i] = 0.0f;
  }
  if (t == nact - 1) {
    float* Tp = ws + WS_T + (long)blockIdx.x * 6;
    #pragma unroll
    for (int i = 0; i < 6; i++) Tp[i] = src[t][i];
  }
}

// ---------------- k2c: inject segment offsets, write chunk entry states ----------------

__global__ __launch_bounds__(1024) void k2c(float* __restrict__ ws) {
  int seg = blockIdx.x & 7, row = blockIdx.x >> 3, t = threadIdx.x;
  __shared__ float sW[36], sG[36], sV[10][36], sT[8][6], sO[6];
  for (int i = t; i < 36; i += 1024) { sW[i] = ws[WS_W + i]; sG[i] = ws[WS_G + i]; }
  for (int i = t; i < 360; i += 1024) sV[i/36][i%36] = ws[WS_V + i];
  if (t < 48) sT[t/6][t%6] = ws[WS_T + ((long)(row*8) + t/6) * 6 + t%6];
  __syncthreads();
  if (t == 0) {
    float o[6] = {0,0,0,0,0,0};
    for (int s2 = 0; s2 < seg; s2++) {
      float no[6];
      #pragma unroll
      for (int i = 0; i < 6; i++) {
        float s = sT[s2][i];
        #pragma unroll
        for (int k = 0; k < 6; k++) s = fmaf(sG[i*6+k], o[k], s);
        no[i] = s;
      }
      #pragma unroll
      for (int i = 0; i < 6; i++) o[i] = no[i];
    }
    #pragma unroll
    for (int i = 0; i < 6; i++) sO[i] = o[i];
  }
  __syncthreads();
  int segstart = seg * SEGCH;
  int nch = min(SEGCH, NCH - segstart);
  int nact = nch >> 1;
  if (t < nact) {
    float e[6];
    #pragma unroll
    for (int i = 0; i < 6; i++) e[i] = sO[i];
    // e = W^(2t) * O via binary decomposition of t (Vk = W^(2*2^k))
    for (int k = 0; k < 10; k++) {
      if ((t >> k) & 1) {
        float ne[6];
        #pragma unroll
        for (int i = 0; i < 6; i++) {
          float s = 0.0f;
          #pragma unroll
          for (int kk = 0; kk < 6; kk++) s = fmaf(sV[k][i*6+kk], e[kk], s);
          ne[i] = s;
        }
        #pragma unroll
        for (int i = 0; i < 6; i++) e[i] = ne[i];
      }
    }
    const float* Er = ws + WS_E + ((long)blockIdx.x * 1024 + t) * 6;
    #pragma unroll
    for (int i = 0; i < 6; i++) e[i] += Er[i];
    // walk 2 chunks: F[j] <- entry(j)
    float* Fj = ws + WS_F + ((long)row * NCH + segstart + 2*t) * 6;
    #pragma unroll
    for (int c = 0; c < 2; c++) {
      float nv[6];
      #pragma unroll
      for (int i = 0; i < 6; i++) {
        float s = Fj[c*6 + i];
        #pragma unroll
        for (int k = 0; k < 6; k++) s = fmaf(sW[i*6+k], e[k], s);
        nv[i] = s;
      }
      #pragma unroll
      for (int i = 0; i < 6; i++) { Fj[c*6 + i] = e[i]; e[i] = nv[i]; }
    }
  }
}

// ---------------- k3: exact emit from entry states ----------------

__global__ __launch_bounds__(256) void k3_emit(const float* __restrict__ x,
                                               float* __restrict__ y,
                                               const float* __restrict__ ws) {
  __shared__ float lds[4 * 2048];
  int wib = threadIdx.x >> 6, lane = threadIdx.x & 63;
  int gw = blockIdx.x * 4 + wib;
  int row = gw / WPR, wci = gw % WPR;
  long rowbase = (long)row * T_LEN;
  int s0 = wci << 11;
  int span4 = (min(2048, T_LEN - s0)) >> 2;
  const float4* xp = (const float4*)(x + rowbase + s0);
  float* slab = lds + (wib << 11);
  if (span4 == 512) {
    #pragma unroll
    for (int i = 0; i < 8; i++) {
      int s = (i << 6) + lane;
      int g = (s & ~7) | ((s & 7) ^ ((s >> 3) & 7));
      GL2LDS(xp + g, slab + (i << 8));
    }
  } else {
    #pragma unroll
    for (int i = 0; i < 8; i++) {
      int s = (i << 6) + lane;
      int g = (s & ~7) | ((s & 7) ^ ((s >> 3) & 7));
      if (g < span4) GL2LDS(xp + g, slab + (i << 8));
    }
  }
  int ci = (wci << 6) + lane;
  float e0=0,e1=0,e2=0,e3=0,e4=0,e5=0;
  if (ci < NCH) {
    const float* E = ws + WS_F + ((long)row * NCH + ci) * 6;
    e0=E[0]; e1=E[1]; e2=E[2]; e3=E[3]; e4=E[4]; e5=E[5];
  }
  __syncthreads();
  if (ci < NCH) {
    const float* cf = ws + WS_COEF;
    LOAD_COEFS(cf);
    float s11=e0, s21=e1, s12=e2, s22=e3, s13=e4, s23=e5;
    int rem = min(CHUNK, T_LEN - (ci << 5));
    int n4 = rem >> 2;
    float* rowp = slab + (lane << 5);
    int xr = lane & 7;
    float y3;
    if (n4 == 8) {
      #pragma unroll
      for (int j4 = 0; j4 < 8; j4++) {
        float* p = rowp + ((j4 ^ xr) << 2);
        float4 v = *(const float4*)p;
        float4 o;
        CASCADE_STEP(v.x); o.x = y3;
        CASCADE_STEP(v.y); o.y = y3;
        CASCADE_STEP(v.z); o.z = y3;
        CASCADE_STEP(v.w); o.w = y3;
        *(float4*)p = o;
      }
    } else {
      for (int j4 = 0; j4 < n4; j4++) {
        float* p = rowp + ((j4 ^ xr) << 2);
        float4 v = *(const float4*)p;
        float4 o;
        CASCADE_STEP(v.x); o.x = y3;
        CASCADE_STEP(v.y); o.y = y3;
        CASCADE_STEP(v.z); o.z = y3;
        CASCADE_STEP(v.w); o.w = y3;
        *(float4*)p = o;
      }
    }
  }
  __syncthreads();
  float4* yp = (float4*)(y + rowbase + s0);
  if (span4 == 512) {
    #pragma unroll
    for (int i = 0; i < 8; i++) {
      int g = (i << 6) + lane;
      int s = (g & ~7) | ((g & 7) ^ ((g >> 3) & 7));
      yp[g] = *(const float4*)(slab + (s << 2));
    }
  } else {
    #pragma unroll
    for (int i = 0; i < 8; i++) {
      int g = (i << 6) + lane;
      int s = (g & ~7) | ((g & 7) ^ ((g >> 3) & 7));
      if (g < span4) yp[g] = *(const float4*)(slab + (s << 2));
    }
  }
}

extern "C" void kernel_launch(void* const* d_in, const int* in_sizes, int n_in,
                              void* d_out, int out_size, void* d_ws, size_t ws_size,
                              hipStream_t stream) {
  const float* audio = (const float*)d_in[0];
  const float* qs    = (const float*)d_in[1];
  const float* gains = (const float*)d_in[2];
  float* out = (float*)d_out;
  float* ws  = (float*)d_ws;

  hipLaunchKernelGGL(k0_setup, dim3(1), dim3(64), 0, stream, qs, gains, ws);
  hipLaunchKernelGGL(k1_states, dim3(NBLK), dim3(256), 0, stream, audio, ws);
  hipLaunchKernelGGL(k2a, dim3(B_ROWS * NSEG), dim3(1024), 0, stream, ws);
  hipLaunchKernelGGL(k2c, dim3(B_ROWS * NSEG), dim3(1024), 0, stream, ws);
  hipLaunchKernelGGL(k3_emit, dim3(NBLK), dim3(256), 0, stream, audio, out, ws);
}